// Round 10
// baseline (293.861 us; speedup 1.0000x reference)
//
#include <hip/hip_runtime.h>
#include <hip/hip_bf16.h>

// Problem: B=4, T=2048, C=1024, H=16, HS=64. M = B*T = 8192.
#define B_ 4
#define T_ 2048
#define C_ 1024
#define H_ 16
#define HS_ 64
#define M_ (B_*T_)
#define QSCALE 0.18033688011112042f   // 0.125 * log2(e): softmax in exp2 domain

typedef __bf16 bf16_t;
typedef bf16_t bf16x8 __attribute__((ext_vector_type(8)));
typedef float f32x4 __attribute__((ext_vector_type(4)));
typedef unsigned short ushort_t;

__device__ __forceinline__ unsigned short f2bf(float f) {
    __hip_bfloat16 h = __float2bfloat16(f);
    return __builtin_bit_cast(unsigned short, h);
}

__device__ __forceinline__ void glds16(const void* g, void* l) {
    __builtin_amdgcn_global_load_lds((const __attribute__((address_space(1))) void*)g,
                                     (__attribute__((address_space(3))) void*)l, 16, 0, 0);
}

// ---------------- prep: x fp32 -> bf16 row-major ----------------
__launch_bounds__(256)
__global__ void cvt_x(const float* __restrict__ in, ushort_t* __restrict__ out) {
    int i = blockIdx.x * 256 + threadIdx.x;   // 8 elems per thread
    const float4* p = (const float4*)in;
    float4 a = p[i * 2], b = p[i * 2 + 1];
    ushort4 o0, o1;
    o0.x = f2bf(a.x); o0.y = f2bf(a.y); o0.z = f2bf(a.z); o0.w = f2bf(a.w);
    o1.x = f2bf(b.x); o1.y = f2bf(b.y); o1.z = f2bf(b.z); o1.w = f2bf(b.w);
    *(ushort4*)&out[i * 8] = o0;
    *(ushort4*)&out[i * 8 + 4] = o1;
}

// ---------------- prep: w [K][N] fp32 -> wT [N][K] bf16 (64x64 LDS tiles) ----------------
__launch_bounds__(256)
__global__ void transpose_cvt(const float* __restrict__ w, ushort_t* __restrict__ wT,
                              int K, int N) {
    __shared__ ushort_t Ts[64][72];
    const int n0 = blockIdx.x * 64, k0 = blockIdx.y * 64;
    const int t = threadIdx.x, r = t >> 2, cq = t & 3;
    #pragma unroll
    for (int j = 0; j < 4; j++) {
        float4 v = *(const float4*)&w[(size_t)(k0 + r) * N + n0 + cq * 16 + j * 4];
        ushort4 o;
        o.x = f2bf(v.x); o.y = f2bf(v.y); o.z = f2bf(v.z); o.w = f2bf(v.w);
        *(ushort4*)&Ts[r][cq * 16 + j * 4] = o;
    }
    __syncthreads();
    #pragma unroll
    for (int j = 0; j < 4; j++) {
        ushort4 o;
        o.x = Ts[cq * 16 + j * 4 + 0][r];
        o.y = Ts[cq * 16 + j * 4 + 1][r];
        o.z = Ts[cq * 16 + j * 4 + 2][r];
        o.w = Ts[cq * 16 + j * 4 + 3][r];
        *(ushort4*)&wT[(size_t)(n0 + r) * K + k0 + cq * 16 + j * 4] = o;
    }
}

// ---------------- QKV GEMM: BK=64, 2-phase recipe, XOR-swizzled LDS ----------------
// LDS slot s of row r holds global chunk s^(r&7). Staging dest linear (glds),
// source chunk pre-swizzled; read slot = (4ks+gl)^(cl&7) -> 2-way only.
__launch_bounds__(256)
__global__ void qkv_gemm(const ushort_t* __restrict__ xb, const ushort_t* __restrict__ wT,
                         const float* __restrict__ bias,
                         ushort_t* __restrict__ qw, ushort_t* __restrict__ kw,
                         ushort_t* __restrict__ vt) {
    const int K = C_;
    __shared__ ushort_t As[2][128 * 64];   // 2 x 16KB
    __shared__ ushort_t Bs[2][128 * 64];
    const int tid = threadIdx.x, lane = tid & 63, wid = tid >> 6;
    const int cl = lane & 15, gl = lane >> 4;
    const int waveM = wid >> 1, waveN = wid & 1;
    const int bid = blockIdx.x;                    // 1536 blocks, XCD-contiguous chunks
    const int swz = (bid & 7) * 192 + (bid >> 3);
    const int by = swz / 24, bx = swz - by * 24;
    const int m0 = by * 128, n0 = bx * 128;
    const int srow = tid >> 3;                     // 0..31
    const int sslot = tid & 7;                     // dest 16B slot
    const int gsw = sslot ^ (srow & 7);            // source chunk (swizzled)
    const int csw = cl & 7;                        // read-side row xor

    f32x4 acc[4][4];
    #pragma unroll
    for (int mf = 0; mf < 4; mf++)
        #pragma unroll
        for (int nf = 0; nf < 4; nf++) acc[mf][nf] = (f32x4)0.0f;

    auto stage = [&](int t, int b) {
        const size_t koff = (size_t)t * 64 + gsw * 8;
        #pragma unroll
        for (int i = 0; i < 4; i++) {
            int row = srow + 32 * i;
            glds16(&xb[(size_t)(m0 + row) * K + koff], &As[b][row * 64 + sslot * 8]);
            glds16(&wT[(size_t)(n0 + row) * K + koff], &Bs[b][row * 64 + sslot * 8]);
        }
    };
    stage(0, 0);
    asm volatile("s_waitcnt vmcnt(0)" ::: "memory");
    __builtin_amdgcn_s_barrier();

    int cur = 0;
    for (int t = 0; t < 16; t++) {
        if (t + 1 < 16) stage(t + 1, cur ^ 1);     // issue early; lands under compute
        bf16x8 a[2][4], b[2][4];
        #pragma unroll
        for (int ks = 0; ks < 2; ks++) {
            #pragma unroll
            for (int mf = 0; mf < 4; mf++) {
                int row = waveM * 64 + mf * 16 + cl;
                a[ks][mf] = *(bf16x8*)&As[cur][row * 64 + 8 * ((4 * ks + gl) ^ csw)];
            }
            #pragma unroll
            for (int nf = 0; nf < 4; nf++) {
                int row = waveN * 64 + nf * 16 + cl;
                b[ks][nf] = *(bf16x8*)&Bs[cur][row * 64 + 8 * ((4 * ks + gl) ^ csw)];
            }
        }
        __builtin_amdgcn_s_setprio(1);
        #pragma unroll
        for (int ks = 0; ks < 2; ks++)
            #pragma unroll
            for (int mf = 0; mf < 4; mf++)
                #pragma unroll
                for (int nf = 0; nf < 4; nf++)
                    acc[mf][nf] = __builtin_amdgcn_mfma_f32_16x16x32_bf16(a[ks][mf], b[ks][nf], acc[mf][nf], 0, 0, 0);
        __builtin_amdgcn_s_setprio(0);
        if (t + 1 < 16) {
            asm volatile("s_waitcnt vmcnt(0)" ::: "memory");
            __builtin_amdgcn_s_barrier();
            cur ^= 1;
        }
    }
    const int secb = n0 >> 10;                // uniform per block
    #pragma unroll
    for (int mf = 0; mf < 4; mf++)
        #pragma unroll
        for (int nf = 0; nf < 4; nf++)
            #pragma unroll
            for (int r = 0; r < 4; r++) {
                int rg = m0 + waveM * 64 + mf * 16 + 4 * gl + r;
                int cg = n0 + waveN * 64 + nf * 16 + cl;
                float val = acc[mf][nf][r] + bias[cg];
                int cc = cg & 1023;
                int h = cc >> 6, hs = cc & 63;
                int bb = rg >> 11, tq = rg & 2047;
                if (secb == 0)
                    qw[(((size_t)(bb * H_ + h)) * T_ + tq) * HS_ + hs] = f2bf(val * QSCALE);
                else if (secb == 1)
                    kw[(((size_t)(bb * H_ + h)) * T_ + tq) * HS_ + hs] = f2bf(val);
                else
                    vt[(((size_t)(bb * H_ + h)) * HS_ + hs) * T_ + tq] = f2bf(val);
            }
}

// ---------------- MFMA flash attention v3: KVBLK=128 + defer-max + setprio ----------------
__launch_bounds__(512, 4)
__global__ void attn_mfma(const ushort_t* __restrict__ qw,
                          const ushort_t* __restrict__ kw,
                          const ushort_t* __restrict__ vt,
                          ushort_t* __restrict__ yw) {
    __shared__ ushort_t Ks[128][72];
    __shared__ ushort_t Vts[64][136];
    __shared__ ushort_t Ps[8][16][136];
    const int tid = threadIdx.x, lane = tid & 63, wid = tid >> 6;
    const int cl = lane & 15, gl = lane >> 4;
    const int qp = blockIdx.x;               // 0..7
    const int bh = blockIdx.y;               // 0..63
    const size_t base = (size_t)bh * T_ * HS_;
    const int bq = bh >> 4, h = bh & 15;
    const int srow = tid >> 3, scq = tid & 7;

    for (int half = 0; half < 2; half++) {
        const int qt = half ? (15 - qp) : qp;
        const int q0 = qt * 128 + wid * 16;
        const int ntiles = qt + 1;

        bf16x8 qf[2];
        #pragma unroll
        for (int kh = 0; kh < 2; kh++)
            qf[kh] = *(const bf16x8*)&qw[base + (size_t)(q0 + cl) * HS_ + kh * 32 + 8 * gl];

        f32x4 o_acc[4];
        #pragma unroll
        for (int dn = 0; dn < 4; dn++) o_acc[dn] = (f32x4)0.0f;
        float m_ = -INFINITY, l_ = 0.f;

        bf16x8 kpre[2], vpre[2], knew[2], vnew[2];
        kpre[0] = *(const bf16x8*)&kw[base + (size_t)srow * HS_ + scq * 8];
        kpre[1] = *(const bf16x8*)&kw[base + (size_t)(64 + srow) * HS_ + scq * 8];
        vpre[0] = *(const bf16x8*)&vt[base + (size_t)srow * T_ + scq * 8];
        vpre[1] = *(const bf16x8*)&vt[base + (size_t)srow * T_ + 64 + scq * 8];

        for (int kt = 0; kt < ntiles; kt++) {
            __syncthreads();
            if (kt + 1 < ntiles) {
                knew[0] = *(const bf16x8*)&kw[base + (size_t)((kt + 1) * 128 + srow) * HS_ + scq * 8];
                knew[1] = *(const bf16x8*)&kw[base + (size_t)((kt + 1) * 128 + 64 + srow) * HS_ + scq * 8];
                vnew[0] = *(const bf16x8*)&vt[base + (size_t)srow * T_ + (kt + 1) * 128 + scq * 8];
                vnew[1] = *(const bf16x8*)&vt[base + (size_t)srow * T_ + (kt + 1) * 128 + 64 + scq * 8];
            }
            *(bf16x8*)&Ks[srow][scq * 8] = kpre[0];
            *(bf16x8*)&Ks[64 + srow][scq * 8] = kpre[1];
            *(bf16x8*)&Vts[srow][scq * 8] = vpre[0];
            *(bf16x8*)&Vts[srow][scq * 8 + 64] = vpre[1];
            __syncthreads();

            {
                const bool full = (kt * 128 + 127 <= q0);

                f32x4 st[8];
                __builtin_amdgcn_s_setprio(1);
                #pragma unroll
                for (int kn = 0; kn < 8; kn++) {
                    bf16x8 kf0 = *(bf16x8*)&Ks[kn * 16 + cl][8 * gl];
                    bf16x8 kf1 = *(bf16x8*)&Ks[kn * 16 + cl][32 + 8 * gl];
                    f32x4 t0 = (f32x4)0.0f;
                    t0 = __builtin_amdgcn_mfma_f32_16x16x32_bf16(kf0, qf[0], t0, 0, 0, 0);
                    st[kn] = __builtin_amdgcn_mfma_f32_16x16x32_bf16(kf1, qf[1], t0, 0, 0, 0);
                }
                __builtin_amdgcn_s_setprio(0);
                if (!full) {
                    const int qg = q0 + cl;
                    #pragma unroll
                    for (int kn = 0; kn < 8; kn++)
                        #pragma unroll
                        for (int r = 0; r < 4; r++) {
                            int kv = kt * 128 + kn * 16 + 4 * gl + r;
                            if (kv > qg) st[kn][r] = -INFINITY;
                        }
                }

                float pmax = st[0][0];
                #pragma unroll
                for (int kn = 0; kn < 8; kn++)
                    #pragma unroll
                    for (int r = 0; r < 4; r++) pmax = fmaxf(pmax, st[kn][r]);
                if (!__all(pmax <= m_ + 8.0f)) {
                    float mx = pmax;
                    mx = fmaxf(mx, __shfl_xor(mx, 16));
                    mx = fmaxf(mx, __shfl_xor(mx, 32));
                    float nm = fmaxf(m_, mx);
                    float al = exp2f(m_ - nm);
                    l_ *= al;
                    #pragma unroll
                    for (int r = 0; r < 4; r++) {
                        float ag = __shfl(al, 4 * gl + r);
                        #pragma unroll
                        for (int dn = 0; dn < 4; dn++) o_acc[dn][r] *= ag;
                    }
                    m_ = nm;
                }

                float ps = 0.f;
                #pragma unroll
                for (int kn = 0; kn < 8; kn++) {
                    float p0 = exp2f(st[kn][0] - m_);
                    float p1 = exp2f(st[kn][1] - m_);
                    float p2 = exp2f(st[kn][2] - m_);
                    float p3 = exp2f(st[kn][3] - m_);
                    ps += (p0 + p1) + (p2 + p3);
                    unsigned lo, hi;
                    asm("v_cvt_pk_bf16_f32 %0, %1, %2" : "=v"(lo) : "v"(p0), "v"(p1));
                    asm("v_cvt_pk_bf16_f32 %0, %1, %2" : "=v"(hi) : "v"(p2), "v"(p3));
                    uint2 wv; wv.x = lo; wv.y = hi;
                    *(uint2*)&Ps[wid][cl][kn * 16 + 4 * gl] = wv;
                }
                l_ += ps;

                bf16x8 pf[4];
                #pragma unroll
                for (int ks = 0; ks < 4; ks++)
                    pf[ks] = *(bf16x8*)&Ps[wid][cl][ks * 32 + 8 * gl];
                __builtin_amdgcn_s_setprio(1);
                #pragma unroll
                for (int dn = 0; dn < 4; dn++)
                    #pragma unroll
                    for (int ks = 0; ks < 4; ks++) {
                        bf16x8 vf = *(bf16x8*)&Vts[dn * 16 + cl][ks * 32 + 8 * gl];
                        o_acc[dn] = __builtin_amdgcn_mfma_f32_16x16x32_bf16(pf[ks], vf, o_acc[dn], 0, 0, 0);
                    }
                __builtin_amdgcn_s_setprio(0);
            }
            #pragma unroll
            for (int i = 0; i < 2; i++) { kpre[i] = knew[i]; vpre[i] = vnew[i]; }
        }

        float ls = l_;
        ls += __shfl_xor(ls, 16);
        ls += __shfl_xor(ls, 32);
        float linv = 1.0f / ls;
        #pragma unroll
        for (int r = 0; r < 4; r++) {
            float lr = __shfl(linv, 4 * gl + r);
            int qg = q0 + 4 * gl + r;
            #pragma unroll
            for (int dn = 0; dn < 4; dn++) {
                int d = dn * 16 + cl;
                yw[((size_t)(bq * T_ + qg)) * C_ + h * HS_ + d] = f2bf(o_acc[dn][r] * lr);
            }
        }
    }
}

// ---------------- Output projection: BK=64, same 2-phase recipe ----------------
__launch_bounds__(256)
__global__ void proj_gemm(const ushort_t* __restrict__ y, const ushort_t* __restrict__ wT,
                          const float* __restrict__ bias, float* __restrict__ out) {
    const int K = C_, N = C_;
    __shared__ ushort_t As[2][128 * 64];
    __shared__ ushort_t Bs[2][128 * 64];
    const int tid = threadIdx.x, lane = tid & 63, wid = tid >> 6;
    const int cl = lane & 15, gl = lane >> 4;
    const int waveM = wid >> 1, waveN = wid & 1;
    const int bid = blockIdx.x;              // 512 blocks
    const int swz = (bid & 7) * 64 + (bid >> 3);
    const int bx = swz & 7, by = swz >> 3;
    const int m0 = by * 128, n0 = bx * 128;
    const int srow = tid >> 3;
    const int sslot = tid & 7;
    const int gsw = sslot ^ (srow & 7);
    const int csw = cl & 7;

    f32x4 acc[4][4];
    #pragma unroll
    for (int mf = 0; mf < 4; mf++)
        #pragma unroll
        for (int nf = 0; nf < 4; nf++) acc[mf][nf] = (f32x4)0.0f;

    auto stage = [&](int t, int b) {
        const size_t koff = (size_t)t * 64 + gsw * 8;
        #pragma unroll
        for (int i = 0; i < 4; i++) {
            int row = srow + 32 * i;
            glds16(&y[(size_t)(m0 + row) * K + koff],  &As[b][row * 64 + sslot * 8]);
            glds16(&wT[(size_t)(n0 + row) * K + koff], &Bs[b][row * 64 + sslot * 8]);
        }
    };
    stage(0, 0);
    asm volatile("s_waitcnt vmcnt(0)" ::: "memory");
    __builtin_amdgcn_s_barrier();

    int cur = 0;
    for (int t = 0; t < 16; t++) {
        if (t + 1 < 16) stage(t + 1, cur ^ 1);
        bf16x8 a[2][4], b[2][4];
        #pragma unroll
        for (int ks = 0; ks < 2; ks++) {
            #pragma unroll
            for (int mf = 0; mf < 4; mf++) {
                int row = waveM * 64 + mf * 16 + cl;
                a[ks][mf] = *(bf16x8*)&As[cur][row * 64 + 8 * ((4 * ks + gl) ^ csw)];
            }
            #pragma unroll
            for (int nf = 0; nf < 4; nf++) {
                int row = waveN * 64 + nf * 16 + cl;
                b[ks][nf] = *(bf16x8*)&Bs[cur][row * 64 + 8 * ((4 * ks + gl) ^ csw)];
            }
        }
        __builtin_amdgcn_s_setprio(1);
        #pragma unroll
        for (int ks = 0; ks < 2; ks++)
            #pragma unroll
            for (int mf = 0; mf < 4; mf++)
                #pragma unroll
                for (int nf = 0; nf < 4; nf++)
                    acc[mf][nf] = __builtin_amdgcn_mfma_f32_16x16x32_bf16(a[ks][mf], b[ks][nf], acc[mf][nf], 0, 0, 0);
        __builtin_amdgcn_s_setprio(0);
        if (t + 1 < 16) {
            asm volatile("s_waitcnt vmcnt(0)" ::: "memory");
            __builtin_amdgcn_s_barrier();
            cur ^= 1;
        }
    }
    #pragma unroll
    for (int mf = 0; mf < 4; mf++)
        #pragma unroll
        for (int nf = 0; nf < 4; nf++)
            #pragma unroll
            for (int r = 0; r < 4; r++) {
                int rg = m0 + waveM * 64 + mf * 16 + 4 * gl + r;
                int cg = n0 + waveN * 64 + nf * 16 + cl;
                out[(size_t)rg * N + cg] = acc[mf][nf][r] + bias[cg];
            }
}

extern "C" void kernel_launch(void* const* d_in, const int* in_sizes, int n_in,
                              void* d_out, int out_size, void* d_ws, size_t ws_size,
                              hipStream_t stream) {
    const float* x      = (const float*)d_in[0];
    const float* w_attn = (const float*)d_in[1];
    const float* b_attn = (const float*)d_in[2];
    const float* w_proj = (const float*)d_in[3];
    const float* b_proj = (const float*)d_in[4];
    float* out = (float*)d_out;

    const size_t E = (size_t)M_ * C_;   // 8388608
    ushort_t* qw  = (ushort_t*)d_ws;
    ushort_t* kw  = qw + E;
    ushort_t* vt  = kw + E;             // [B,H,HS,T]
    ushort_t* xy  = vt + E;             // xb during qkv, then yw [B,T,C]
    ushort_t* wat = xy + E;             // w_attn^T [3072][1024]
    ushort_t* wpt = wat + 3 * (size_t)C_ * C_;   // w_proj^T [1024][1024]

    cvt_x<<<dim3(4096), 256, 0, stream>>>(x, xy);
    transpose_cvt<<<dim3(48, 16), 256, 0, stream>>>(w_attn, wat, C_, 3 * C_);
    transpose_cvt<<<dim3(16, 16), 256, 0, stream>>>(w_proj, wpt, C_, C_);
    qkv_gemm<<<dim3(1536), 256, 0, stream>>>(xy, wat, b_attn, qw, kw, vt);
    attn_mfma<<<dim3(8, 64), 512, 0, stream>>>(qw, kw, vt, xy);
    proj_gemm<<<dim3(512), 256, 0, stream>>>(xy, wpt, b_proj, out);
}